// Round 11
// baseline (3172.053 us; speedup 1.0000x reference)
//
#include <hip/hip_runtime.h>
#include <math.h>

// ESN: 512 sequential steps of h = tanh([h | x_t] @ [W_hh|W_ih]^T + b)
// T=512, B=64, I=128, H=1024, K' = 1152.
//
// R15 (isolation experiment; R12 @ 2.77 ms, R14 @ 2.95 ms):
//   R14 = R12 + {packed FMA, fragmented 4B epilogue}  -> regressed.
//   R15 = R12 + {packed FMA only}: epilogue reverted to R12's 8-lane,
//   16B-atomic dwordx4 publication (consumers poll 16B chunks -- per-dword
//   publication in R14 likely multiplied partial-visibility retries).
//  * v_pk_fma_f32 (VOP3P, 2 fp32 FMA/instr; op_sel broadcasts the h scalar
//    so no extra movs): main FMA VALU time 0.96 -> 0.48 us/step (R14-proven:
//    VALUBusy 36.2 -> 26.6%, VGPR 100 -> 80).
//  * Everything else byte-for-byte R12: sentinel sync (out pre-poisoned
//    0x7F7F7F7F, data IS the flag, fire-and-forget sc0sc1 stores, no
//    flags/no drain), wave-wide 4-producer poll, R9 mapping + wave-private
//    k-slice staging (no pre-FMA barrier), one __syncthreads/step,
//    parity-dbuf red[], W+bias VGPR-resident all 512 steps, x prefetch.

#define T_STEPS 512
#define BATCH   64
#define HDIM    1024
#define IDIM    128
#define KDIM    1152
#define NWG     256
#define NB      8
#define POISON  0x7F7F7F7Fu

typedef float f32x4_t __attribute__((ext_vector_type(4)));
typedef float f32x2_t __attribute__((ext_vector_type(2)));

// d.{lo,hi} += w.{lo,hi} * h.lo   (broadcast LOW half of h-pair)
__device__ __forceinline__ void pk_fma_lo(f32x2_t& d, f32x2_t w, f32x2_t h) {
    asm("v_pk_fma_f32 %0, %1, %2, %0 op_sel_hi:[1,0,1]"
        : "+v"(d) : "v"(w), "v"(h));
}
// d.{lo,hi} += w.{lo,hi} * h.hi   (broadcast HIGH half of h-pair)
__device__ __forceinline__ void pk_fma_hi(f32x2_t& d, f32x2_t w, f32x2_t h) {
    asm("v_pk_fma_f32 %0, %1, %2, %0 op_sel:[0,1,0]"
        : "+v"(d) : "v"(w), "v"(h));
}

// 4 x 16B coherence-point loads from 4 addresses, single drain.
__device__ __forceinline__ void sc_load4x4(const float* p0, const float* p1,
                                           const float* p2, const float* p3,
                                           float4& a, float4& b,
                                           float4& c, float4& d) {
    asm volatile(
        "global_load_dwordx4 %0, %4, off sc0 sc1\n\t"
        "global_load_dwordx4 %1, %5, off sc0 sc1\n\t"
        "global_load_dwordx4 %2, %6, off sc0 sc1\n\t"
        "global_load_dwordx4 %3, %7, off sc0 sc1\n\t"
        "s_waitcnt vmcnt(0)"
        : "=&v"(a), "=&v"(b), "=&v"(c), "=&v"(d)
        : "v"(p0), "v"(p1), "v"(p2), "v"(p3)
        : "memory");
}

// 16B write-through store (no drain: visibility rides the write; consumers
// poll the data itself). 16B single-instruction publication keeps the
// consumer's 16B poll chunk near-atomic.
__device__ __forceinline__ void sc_store4_nodrain(float* p, float4 v) {
    f32x4_t t;
    t.x = v.x; t.y = v.y; t.z = v.z; t.w = v.w;
    asm volatile("global_store_dwordx4 %0, %1, off sc0 sc1"
                 :: "v"(p), "v"(t) : "memory");
}

__device__ __forceinline__ unsigned chk4(float4 v) {
    return (unsigned)((__float_as_uint(v.x) == POISON) |
                      (__float_as_uint(v.y) == POISON) |
                      (__float_as_uint(v.z) == POISON) |
                      (__float_as_uint(v.w) == POISON));
}

// src[R][C] -> dst[C][R], 64x64 LDS tiles, grid = (C/64)*(R/64), 256 thr
__global__ void transpose_f32(const float* __restrict__ src, float* __restrict__ dst,
                              int R, int C) {
    __shared__ float tile[64][65];
    const int tcol = threadIdx.x & 63;
    const int trow = threadIdx.x >> 6;
    const int nbx = C >> 6;
    const int bx = blockIdx.x % nbx;
    const int by = blockIdx.x / nbx;
    const int c0 = bx << 6, r0 = by << 6;
    for (int i = trow; i < 64; i += 4)
        tile[i][tcol] = src[(size_t)(r0 + i) * C + c0 + tcol];
    __syncthreads();
    for (int i = trow; i < 64; i += 4)
        dst[(size_t)(c0 + i) * R + r0 + tcol] = tile[tcol][i];
}

__global__ __launch_bounds__(512) void esn_persistent(
    const float* __restrict__ x,     // [512][64][128]
    const float* __restrict__ h0,    // [64][1024]
    const float* __restrict__ WT,    // [1152][1024]
    const float* __restrict__ bias,  // [1024]
    float* __restrict__ out,         // [512][64][1024] (pre-poisoned)
    float* __restrict__ hfin)        // [64][1024]
{
    const int tid  = threadIdx.x;
    const int wg   = blockIdx.x;
    const int wave = tid >> 6;                       // 0..7 (k-slice / epi row)
    const int lane = tid & 63;
    const int jq   = lane & 7;                       // 4 j each -> 32 j
    const int ksub = lane >> 3;                      // 0..7 k-interleave
    const int jblk = ((wg & 7) << 2) | ((wg >> 3) & 3);  // XCD owns 4 jblks
    const int bgrp = wg >> 5;                            // 0..7
    const int b0   = bgrp << 3;
    const int j0   = (jblk << 5) + (jq << 2);
    const int krec = wave << 7;                      // recurrent k base (128/wave)
    const int kx   = HDIM + (wave << 4) + (ksub << 1);  // x-part rows (2 each)

    // wave-private staging blocks
    __shared__ float  ht2[8 * 1024];                 // [wave][8 rows][128 k] 32KB
    __shared__ float  htx[8 * 128];                  // [wave][8 rows][16 xk]  4KB
    __shared__ float4 red[2][8 * 8 * 9];             // parity-dbuf reduce    18KB

    // ---- hoist all 18 W vec4 loads for ALL 512 steps (72 VGPRs) ----
    f32x4_t Wv[18];
    {
        const float* wp = WT + (size_t)krec * HDIM + j0;
        #pragma unroll
        for (int i = 0; i < 4; ++i) {
            const int kk = ((i << 3) + ksub) << 2;      // 0..124 step 4
            const float* wk = wp + (size_t)kk * HDIM;
            Wv[i * 4 + 0] = *(const f32x4_t*)(wk);
            Wv[i * 4 + 1] = *(const f32x4_t*)(wk + HDIM);
            Wv[i * 4 + 2] = *(const f32x4_t*)(wk + 2 * HDIM);
            Wv[i * 4 + 3] = *(const f32x4_t*)(wk + 3 * HDIM);
        }
        const float* wkx = WT + (size_t)kx * HDIM + j0;
        Wv[16] = *(const f32x4_t*)(wkx);
        Wv[17] = *(const f32x4_t*)(wkx + HDIM);
    }

    // ---- epilogue constants: lanes 0-7 of wave v handle row b0+v ----
    float4 b4 = make_float4(0.f, 0.f, 0.f, 0.f);
    int jj = 0;
    if (lane < 8) {
        jj = (jblk << 5) + (lane << 2);
        b4 = *(const float4*)(bias + jj);
    }

    // ---- staging lane maps ----
    const int sbb = lane >> 5;                 // row parity (0/1)
    const int sko = (lane & 31) << 2;          // k-offset within slice
    float* hdst = ht2 + (wave << 10) + (lane << 2);      // contiguous 1KB/instr
    const int xr = lane >> 3;                  // x row
    const int xco = (lane & 7) << 1;           // x col-offset within slice
    float* xdst = htx + (wave << 7) + (xr << 4) + xco;
    const float* hb = ht2 + (wave << 10);
    const float* xb = htx + (wave << 7);

    // ---- prefetch x slice for t=0 (plain cached load, x read-only) ----
    float2 xv2 = *(const float2*)(x + (size_t)(b0 + xr) * IDIM + (wave << 4) + xco);

    for (int t = 0; t < T_STEPS; ++t) {
        // ---- stage this wave's k-slice of 8 rows into wave-private LDS ----
        *(float2*)xdst = xv2;
        if (t == 0) {
            const float* p = h0 + (size_t)(b0 + sbb) * HDIM + krec + sko;
            *(float4*)(hdst)       = *(const float4*)(p);
            *(float4*)(hdst + 256) = *(const float4*)(p + 2 * HDIM);
            *(float4*)(hdst + 512) = *(const float4*)(p + 4 * HDIM);
            *(float4*)(hdst + 768) = *(const float4*)(p + 6 * HDIM);
        } else {
            // sentinel poll: data IS the flag (wave-wide over all 4 producers)
            const float* p = out + ((size_t)(t - 1) * BATCH + b0 + sbb) * HDIM
                             + krec + sko;
            float4 a, b, c, d;
            do {
                sc_load4x4(p, p + 2 * HDIM, p + 4 * HDIM, p + 6 * HDIM,
                           a, b, c, d);
            } while (__any((int)(chk4(a) | chk4(b) | chk4(c) | chk4(d))));
            *(float4*)(hdst)       = a;
            *(float4*)(hdst + 256) = b;
            *(float4*)(hdst + 512) = c;
            *(float4*)(hdst + 768) = d;
        }
        // NO __syncthreads: staged data is wave-private.

        // prefetch next x slice; latency hides under the FMA phase
        if (t + 1 < T_STEPS)
            xv2 = *(const float2*)(x + ((size_t)(t + 1) * BATCH + b0 + xr) * IDIM
                                   + (wave << 4) + xco);

        // ---- packed FMA: accx = (j0,j1), accz = (j2,j3) per row ----
        f32x2_t accx[NB], accz[NB];
        #pragma unroll
        for (int bb = 0; bb < NB; ++bb) {
            accx[bb] = (f32x2_t){0.f, 0.f};
            accz[bb] = (f32x2_t){0.f, 0.f};
        }

        #pragma unroll
        for (int i = 0; i < 4; ++i) {
            const int ko = ((i << 3) + ksub) << 2;       // 0..124 step 4
            const f32x2_t w0x = Wv[i * 4 + 0].xy, w0z = Wv[i * 4 + 0].zw;
            const f32x2_t w1x = Wv[i * 4 + 1].xy, w1z = Wv[i * 4 + 1].zw;
            const f32x2_t w2x = Wv[i * 4 + 2].xy, w2z = Wv[i * 4 + 2].zw;
            const f32x2_t w3x = Wv[i * 4 + 3].xy, w3z = Wv[i * 4 + 3].zw;
            #pragma unroll
            for (int bb = 0; bb < NB; ++bb) {
                const f32x4_t h4 = *(const f32x4_t*)(hb + (bb << 7) + ko);
                const f32x2_t h01 = h4.xy, h23 = h4.zw;
                pk_fma_lo(accx[bb], w0x, h01);   // k0
                pk_fma_lo(accz[bb], w0z, h01);
                pk_fma_hi(accx[bb], w1x, h01);   // k1
                pk_fma_hi(accz[bb], w1z, h01);
                pk_fma_lo(accx[bb], w2x, h23);   // k2
                pk_fma_lo(accz[bb], w2z, h23);
                pk_fma_hi(accx[bb], w3x, h23);   // k3
                pk_fma_hi(accz[bb], w3z, h23);
            }
        }
        // x tail: 2 k per thread
        {
            const f32x2_t w16x = Wv[16].xy, w16z = Wv[16].zw;
            const f32x2_t w17x = Wv[17].xy, w17z = Wv[17].zw;
            #pragma unroll
            for (int bb = 0; bb < NB; ++bb) {
                const f32x2_t hx = *(const f32x2_t*)(xb + (bb << 4) + (ksub << 1));
                pk_fma_lo(accx[bb], w16x, hx);
                pk_fma_lo(accz[bb], w16z, hx);
                pk_fma_hi(accx[bb], w17x, hx);
                pk_fma_hi(accz[bb], w17z, hx);
            }
        }

        // ---- reduce over ksub (lane bits 3,4,5) ----
        #pragma unroll
        for (int bb = 0; bb < NB; ++bb) {
            float a0 = accx[bb].x, a1 = accx[bb].y;
            float a2 = accz[bb].x, a3 = accz[bb].y;
            a0 += __shfl_xor(a0, 8);  a1 += __shfl_xor(a1, 8);
            a2 += __shfl_xor(a2, 8);  a3 += __shfl_xor(a3, 8);
            a0 += __shfl_xor(a0, 16); a1 += __shfl_xor(a1, 16);
            a2 += __shfl_xor(a2, 16); a3 += __shfl_xor(a3, 16);
            a0 += __shfl_xor(a0, 32); a1 += __shfl_xor(a1, 32);
            a2 += __shfl_xor(a2, 32); a3 += __shfl_xor(a3, 32);
            if (ksub == 0)
                red[t & 1][((wave << 3) + jq) * 9 + bb] =
                    make_float4(a0, a1, a2, a3);
        }
        __syncthreads();                               // red[t&1] complete

        // ---- per-wave epilogue for row b0+wave: lanes 0-7 (R12-proven) ----
        if (lane < 8) {
            float4 s = make_float4(0.f, 0.f, 0.f, 0.f);
            #pragma unroll
            for (int w = 0; w < 8; ++w) {
                float4 r = red[t & 1][((w << 3) + lane) * 9 + wave];
                s.x += r.x; s.y += r.y; s.z += r.z; s.w += r.w;
            }
            float4 o;
            o.x = tanhf(s.x + b4.x);
            o.y = tanhf(s.y + b4.y);
            o.z = tanhf(s.z + b4.z);
            o.w = tanhf(s.w + b4.w);
            // fire-and-forget 16B write-through: the store itself is the signal
            sc_store4_nodrain(out + ((size_t)t * BATCH + b0 + wave) * HDIM + jj, o);
            if (t == T_STEPS - 1)
                *(float4*)(hfin + (size_t)(b0 + wave) * HDIM + jj) = o;
        }
    }
}

extern "C" void kernel_launch(void* const* d_in, const int* in_sizes, int n_in,
                              void* d_out, int out_size, void* d_ws, size_t ws_size,
                              hipStream_t stream) {
    const float* x    = (const float*)d_in[0];
    const float* h0   = (const float*)d_in[1];
    const float* w_ih = (const float*)d_in[2];   // [1024][128]
    const float* w_hh = (const float*)d_in[3];   // [1024][1024]
    const float* bias = (const float*)d_in[4];   // [1024]
    float* out = (float*)d_out;

    char* ws = (char*)d_ws;
    float* WT = (float*)ws;                      // [1152][1024] = 4.72 MB

    // poison the polled region: byte 0x7F -> dword 0x7F7F7F7F = 3.4e38,
    // unreachable by tanh. Stream-ordered; re-arms on every replay.
    (void)hipMemsetAsync(out, 0x7F,
                         (size_t)T_STEPS * BATCH * HDIM * sizeof(float), stream);
    transpose_f32<<<256, 256, 0, stream>>>(w_hh, WT, HDIM, HDIM);
    transpose_f32<<<32, 256, 0, stream>>>(w_ih, WT + (size_t)HDIM * HDIM, HDIM, IDIM);
    esn_persistent<<<NWG, 512, 0, stream>>>(x, h0, WT, bias,
                                            out, out + (size_t)T_STEPS * BATCH * HDIM);
}

// Round 12
// 2836.653 us; speedup vs baseline: 1.1182x; 1.1182x over previous
//
#include <hip/hip_runtime.h>
#include <math.h>

// ESN: 512 sequential steps of h = tanh([h | x_t] @ [W_hh|W_ih]^T + b)
// T=512, B=64, I=128, H=1024, K' = 1152.
//
// R16 (from R12 @ 2.77 ms; R14/R15 proved pk_fma asm regresses -- reverted):
// R12 + cheap poll retries.
//  * Per-lane done-masking in the sentinel poll: a lane whose 4 chunks are
//    already non-poison stops re-loading (exec-masked). Poll traffic decays
//    as producers land, instead of all 64 lanes x 16B hammering the
//    coherence point every ~0.3us (2048 waves ~= 7 TB/s of MALL pressure
//    that delays the very stores being awaited).
//  * s_sleep(2) (~128cy) between retry rounds: bounds the poll rate; adds
//    at most ~53ns quantization to the observe time.
//  * Everything else byte-for-byte R12 (proven best): sentinel sync (out
//    pre-poisoned 0x7F7F7F7F, data IS the flag, fire-and-forget sc0sc1
//    dwordx4 stores, no flags/no drain), plain-fmaf compiler-scheduled FMA,
//    R9 mapping + wave-private k-slice staging (no pre-FMA barrier), one
//    __syncthreads/step, parity-dbuf red[], W (18 float4) + bias
//    VGPR-resident all 512 steps, 8-lane epilogue, x prefetch.

#define T_STEPS 512
#define BATCH   64
#define HDIM    1024
#define IDIM    128
#define KDIM    1152
#define NWG     256
#define NB      8
#define POISON  0x7F7F7F7Fu

typedef float f32x4_t __attribute__((ext_vector_type(4)));

// 4 x 16B coherence-point loads from 4 addresses, single drain.
__device__ __forceinline__ void sc_load4x4(const float* p0, const float* p1,
                                           const float* p2, const float* p3,
                                           float4& a, float4& b,
                                           float4& c, float4& d) {
    asm volatile(
        "global_load_dwordx4 %0, %4, off sc0 sc1\n\t"
        "global_load_dwordx4 %1, %5, off sc0 sc1\n\t"
        "global_load_dwordx4 %2, %6, off sc0 sc1\n\t"
        "global_load_dwordx4 %3, %7, off sc0 sc1\n\t"
        "s_waitcnt vmcnt(0)"
        : "=&v"(a), "=&v"(b), "=&v"(c), "=&v"(d)
        : "v"(p0), "v"(p1), "v"(p2), "v"(p3)
        : "memory");
}

// 16B write-through store (no drain: visibility rides the write; consumers
// poll the data itself)
__device__ __forceinline__ void sc_store4_nodrain(float* p, float4 v) {
    f32x4_t t;
    t.x = v.x; t.y = v.y; t.z = v.z; t.w = v.w;
    asm volatile("global_store_dwordx4 %0, %1, off sc0 sc1"
                 :: "v"(p), "v"(t) : "memory");
}

__device__ __forceinline__ unsigned chk4(float4 v) {
    return (unsigned)((__float_as_uint(v.x) == POISON) |
                      (__float_as_uint(v.y) == POISON) |
                      (__float_as_uint(v.z) == POISON) |
                      (__float_as_uint(v.w) == POISON));
}

// src[R][C] -> dst[C][R], 64x64 LDS tiles, grid = (C/64)*(R/64), 256 thr
__global__ void transpose_f32(const float* __restrict__ src, float* __restrict__ dst,
                              int R, int C) {
    __shared__ float tile[64][65];
    const int tcol = threadIdx.x & 63;
    const int trow = threadIdx.x >> 6;
    const int nbx = C >> 6;
    const int bx = blockIdx.x % nbx;
    const int by = blockIdx.x / nbx;
    const int c0 = bx << 6, r0 = by << 6;
    for (int i = trow; i < 64; i += 4)
        tile[i][tcol] = src[(size_t)(r0 + i) * C + c0 + tcol];
    __syncthreads();
    for (int i = trow; i < 64; i += 4)
        dst[(size_t)(c0 + i) * R + r0 + tcol] = tile[tcol][i];
}

__global__ __launch_bounds__(512) void esn_persistent(
    const float* __restrict__ x,     // [512][64][128]
    const float* __restrict__ h0,    // [64][1024]
    const float* __restrict__ WT,    // [1152][1024]
    const float* __restrict__ bias,  // [1024]
    float* __restrict__ out,         // [512][64][1024] (pre-poisoned)
    float* __restrict__ hfin)        // [64][1024]
{
    const int tid  = threadIdx.x;
    const int wg   = blockIdx.x;
    const int wave = tid >> 6;                       // 0..7 (k-slice / epi row)
    const int lane = tid & 63;
    const int jq   = lane & 7;                       // 4 j each -> 32 j
    const int ksub = lane >> 3;                      // 0..7 k-interleave
    const int jblk = ((wg & 7) << 2) | ((wg >> 3) & 3);  // XCD owns 4 jblks
    const int bgrp = wg >> 5;                            // 0..7
    const int b0   = bgrp << 3;
    const int j0   = (jblk << 5) + (jq << 2);
    const int krec = wave << 7;                      // recurrent k base (128/wave)
    const int kx   = HDIM + (wave << 4) + (ksub << 1);  // x-part rows (2 each)

    // wave-private staging blocks
    __shared__ float  ht2[8 * 1024];                 // [wave][8 rows][128 k] 32KB
    __shared__ float  htx[8 * 128];                  // [wave][8 rows][16 xk]  4KB
    __shared__ float4 red[2][8 * 8 * 9];             // parity-dbuf reduce    18KB

    // ---- hoist all 18 W float4 loads for ALL 512 steps (72 VGPRs) ----
    float4 Wv[18];
    {
        const float* wp = WT + (size_t)krec * HDIM + j0;
        #pragma unroll
        for (int i = 0; i < 4; ++i) {
            const int kk = ((i << 3) + ksub) << 2;      // 0..124 step 4
            const float* wk = wp + (size_t)kk * HDIM;
            Wv[i * 4 + 0] = *(const float4*)(wk);
            Wv[i * 4 + 1] = *(const float4*)(wk + HDIM);
            Wv[i * 4 + 2] = *(const float4*)(wk + 2 * HDIM);
            Wv[i * 4 + 3] = *(const float4*)(wk + 3 * HDIM);
        }
        const float* wkx = WT + (size_t)kx * HDIM + j0;
        Wv[16] = *(const float4*)(wkx);
        Wv[17] = *(const float4*)(wkx + HDIM);
    }

    // ---- epilogue constants: lanes 0-7 of wave v handle row b0+v ----
    float4 b4 = make_float4(0.f, 0.f, 0.f, 0.f);
    int jj = 0;
    if (lane < 8) {
        jj = (jblk << 5) + (lane << 2);
        b4 = *(const float4*)(bias + jj);
    }

    // ---- staging lane maps ----
    const int sbb = lane >> 5;                 // row parity (0/1)
    const int sko = (lane & 31) << 2;          // k-offset within slice
    float* hdst = ht2 + (wave << 10) + (lane << 2);      // contiguous 1KB/instr
    const int xr = lane >> 3;                  // x row
    const int xco = (lane & 7) << 1;           // x col-offset within slice
    float* xdst = htx + (wave << 7) + (xr << 4) + xco;
    const float* hb = ht2 + (wave << 10);
    const float* xb = htx + (wave << 7);

    // ---- prefetch x slice for t=0 (plain cached load, x read-only) ----
    float2 xv2 = *(const float2*)(x + (size_t)(b0 + xr) * IDIM + (wave << 4) + xco);

    for (int t = 0; t < T_STEPS; ++t) {
        // ---- stage this wave's k-slice of 8 rows into wave-private LDS ----
        *(float2*)xdst = xv2;
        if (t == 0) {
            const float* p = h0 + (size_t)(b0 + sbb) * HDIM + krec + sko;
            *(float4*)(hdst)       = *(const float4*)(p);
            *(float4*)(hdst + 256) = *(const float4*)(p + 2 * HDIM);
            *(float4*)(hdst + 512) = *(const float4*)(p + 4 * HDIM);
            *(float4*)(hdst + 768) = *(const float4*)(p + 6 * HDIM);
        } else {
            // sentinel poll: data IS the flag. Per-lane done-masking: lanes
            // with all 4 chunks clean stop re-loading; s_sleep(2) bounds
            // the retry rate (poll traffic decays as producers land).
            const float* p = out + ((size_t)(t - 1) * BATCH + b0 + sbb) * HDIM
                             + krec + sko;
            float4 a, b, c, d;
            sc_load4x4(p, p + 2 * HDIM, p + 4 * HDIM, p + 6 * HDIM, a, b, c, d);
            bool done = !(chk4(a) | chk4(b) | chk4(c) | chk4(d));
            while (!__all((int)done)) {
                __builtin_amdgcn_s_sleep(2);
                if (!done) {
                    sc_load4x4(p, p + 2 * HDIM, p + 4 * HDIM, p + 6 * HDIM,
                               a, b, c, d);
                    done = !(chk4(a) | chk4(b) | chk4(c) | chk4(d));
                }
            }
            *(float4*)(hdst)       = a;
            *(float4*)(hdst + 256) = b;
            *(float4*)(hdst + 512) = c;
            *(float4*)(hdst + 768) = d;
        }
        // NO __syncthreads: staged data is wave-private.

        // prefetch next x slice; latency hides under the FMA phase
        if (t + 1 < T_STEPS)
            xv2 = *(const float2*)(x + ((size_t)(t + 1) * BATCH + b0 + xr) * IDIM
                                   + (wave << 4) + xco);

        // ---- FMA: acc[b] over this thread's k (W in registers) ----
        float4 acc[NB];
        #pragma unroll
        for (int bb = 0; bb < NB; ++bb) acc[bb] = make_float4(0.f, 0.f, 0.f, 0.f);

        #pragma unroll
        for (int i = 0; i < 4; ++i) {
            const int ko = ((i << 3) + ksub) << 2;       // 0..124 step 4
            const float4 w0 = Wv[i * 4 + 0], w1 = Wv[i * 4 + 1];
            const float4 w2 = Wv[i * 4 + 2], w3 = Wv[i * 4 + 3];
            #pragma unroll
            for (int bb = 0; bb < NB; ++bb) {
                float4 h4 = *(const float4*)(hb + (bb << 7) + ko);
                acc[bb].x = fmaf(w0.x, h4.x, acc[bb].x);
                acc[bb].y = fmaf(w0.y, h4.x, acc[bb].y);
                acc[bb].z = fmaf(w0.z, h4.x, acc[bb].z);
                acc[bb].w = fmaf(w0.w, h4.x, acc[bb].w);
                acc[bb].x = fmaf(w1.x, h4.y, acc[bb].x);
                acc[bb].y = fmaf(w1.y, h4.y, acc[bb].y);
                acc[bb].z = fmaf(w1.z, h4.y, acc[bb].z);
                acc[bb].w = fmaf(w1.w, h4.y, acc[bb].w);
                acc[bb].x = fmaf(w2.x, h4.z, acc[bb].x);
                acc[bb].y = fmaf(w2.y, h4.z, acc[bb].y);
                acc[bb].z = fmaf(w2.z, h4.z, acc[bb].z);
                acc[bb].w = fmaf(w2.w, h4.z, acc[bb].w);
                acc[bb].x = fmaf(w3.x, h4.w, acc[bb].x);
                acc[bb].y = fmaf(w3.y, h4.w, acc[bb].y);
                acc[bb].z = fmaf(w3.z, h4.w, acc[bb].z);
                acc[bb].w = fmaf(w3.w, h4.w, acc[bb].w);
            }
        }
        // x tail: 2 k per thread
        #pragma unroll
        for (int bb = 0; bb < NB; ++bb) {
            float2 hx = *(const float2*)(xb + (bb << 4) + (ksub << 1));
            acc[bb].x = fmaf(Wv[16].x, hx.x, acc[bb].x);
            acc[bb].y = fmaf(Wv[16].y, hx.x, acc[bb].y);
            acc[bb].z = fmaf(Wv[16].z, hx.x, acc[bb].z);
            acc[bb].w = fmaf(Wv[16].w, hx.x, acc[bb].w);
            acc[bb].x = fmaf(Wv[17].x, hx.y, acc[bb].x);
            acc[bb].y = fmaf(Wv[17].y, hx.y, acc[bb].y);
            acc[bb].z = fmaf(Wv[17].z, hx.y, acc[bb].z);
            acc[bb].w = fmaf(Wv[17].w, hx.y, acc[bb].w);
        }

        // ---- reduce over ksub (lane bits 3,4,5) ----
        #pragma unroll
        for (int bb = 0; bb < NB; ++bb) {
            acc[bb].x += __shfl_xor(acc[bb].x, 8);
            acc[bb].y += __shfl_xor(acc[bb].y, 8);
            acc[bb].z += __shfl_xor(acc[bb].z, 8);
            acc[bb].w += __shfl_xor(acc[bb].w, 8);
            acc[bb].x += __shfl_xor(acc[bb].x, 16);
            acc[bb].y += __shfl_xor(acc[bb].y, 16);
            acc[bb].z += __shfl_xor(acc[bb].z, 16);
            acc[bb].w += __shfl_xor(acc[bb].w, 16);
            acc[bb].x += __shfl_xor(acc[bb].x, 32);
            acc[bb].y += __shfl_xor(acc[bb].y, 32);
            acc[bb].z += __shfl_xor(acc[bb].z, 32);
            acc[bb].w += __shfl_xor(acc[bb].w, 32);
        }
        if (ksub == 0) {
            #pragma unroll
            for (int bb = 0; bb < NB; ++bb)
                red[t & 1][((wave << 3) + jq) * 9 + bb] = acc[bb];
        }
        __syncthreads();                               // red[t&1] complete

        // ---- per-wave epilogue for row b0+wave: lanes 0-7 ----
        if (lane < 8) {
            float4 s = make_float4(0.f, 0.f, 0.f, 0.f);
            #pragma unroll
            for (int w = 0; w < 8; ++w) {
                float4 r = red[t & 1][((w << 3) + lane) * 9 + wave];
                s.x += r.x; s.y += r.y; s.z += r.z; s.w += r.w;
            }
            float4 o;
            o.x = tanhf(s.x + b4.x);
            o.y = tanhf(s.y + b4.y);
            o.z = tanhf(s.z + b4.z);
            o.w = tanhf(s.w + b4.w);
            // fire-and-forget write-through: the store itself is the signal
            sc_store4_nodrain(out + ((size_t)t * BATCH + b0 + wave) * HDIM + jj, o);
            if (t == T_STEPS - 1)
                *(float4*)(hfin + (size_t)(b0 + wave) * HDIM + jj) = o;
        }
    }
}

extern "C" void kernel_launch(void* const* d_in, const int* in_sizes, int n_in,
                              void* d_out, int out_size, void* d_ws, size_t ws_size,
                              hipStream_t stream) {
    const float* x    = (const float*)d_in[0];
    const float* h0   = (const float*)d_in[1];
    const float* w_ih = (const float*)d_in[2];   // [1024][128]
    const float* w_hh = (const float*)d_in[3];   // [1024][1024]
    const float* bias = (const float*)d_in[4];   // [1024]
    float* out = (float*)d_out;

    char* ws = (char*)d_ws;
    float* WT = (float*)ws;                      // [1152][1024] = 4.72 MB

    // poison the polled region: byte 0x7F -> dword 0x7F7F7F7F = 3.4e38,
    // unreachable by tanh. Stream-ordered; re-arms on every replay.
    (void)hipMemsetAsync(out, 0x7F,
                         (size_t)T_STEPS * BATCH * HDIM * sizeof(float), stream);
    transpose_f32<<<256, 256, 0, stream>>>(w_hh, WT, HDIM, HDIM);
    transpose_f32<<<32, 256, 0, stream>>>(w_ih, WT + (size_t)HDIM * HDIM, HDIM, IDIM);
    esn_persistent<<<NWG, 512, 0, stream>>>(x, h0, WT, bias,
                                            out, out + (size_t)T_STEPS * BATCH * HDIM);
}